// Round 1
// baseline (11.284 us; speedup 1.0000x reference)
//
#include <hip/hip_runtime.h>
#include <math.h>

// Problem constants from the reference
#define BB 16
#define TT 100
#define VV 50000
#define SS 4
#define NTHREADS 1024

__global__ __launch_bounds__(NTHREADS)
void bpr_loss_kernel(const float* __restrict__ output,
                     const int*   __restrict__ labels,
                     const int*   __restrict__ x_lens,
                     const int*   __restrict__ neg_ids,
                     float*       __restrict__ out) {
    const int tid = threadIdx.x;

    float acc = 0.0f;

    // One (b, t) pair per iteration; B*T = 1600 total pairs.
    for (int i = tid; i < BB * TT; i += NTHREADS) {
        const int b = i / TT;
        const int t = i - b * TT;
        const int xl = x_lens[b];
        if (t < xl) {
            const float* row = output + (size_t)i * VV;     // output[b, t, :]
            const float  pos = row[labels[i]];
            const int*   nid = neg_ids + (size_t)i * SS;
            float s_sum = 0.0f;
            #pragma unroll
            for (int s = 0; s < SS; ++s) {
                const float neg = row[nid[s]];
                const float x   = pos - neg;
                // log_sigmoid(x) = min(x,0) - log1p(exp(-|x|))  (stable)
                const float ls  = fminf(x, 0.0f) - log1pf(__expf(-fabsf(x)));
                s_sum += ls;
            }
            acc += s_sum / (float)xl;
        }
    }

    // Deterministic block reduction: wave-64 shuffle tree, then LDS across waves.
    #pragma unroll
    for (int off = 32; off > 0; off >>= 1)
        acc += __shfl_down(acc, off, 64);

    __shared__ float wave_sums[NTHREADS / 64];
    const int wave = tid >> 6;
    if ((tid & 63) == 0) wave_sums[wave] = acc;
    __syncthreads();

    if (tid < NTHREADS / 64) {
        float v = wave_sums[tid];
        #pragma unroll
        for (int off = (NTHREADS / 64) / 2; off > 0; off >>= 1)
            v += __shfl_down(v, off, NTHREADS / 64);
        if (tid == 0)
            out[0] = -v / (float)BB;
    }
}

extern "C" void kernel_launch(void* const* d_in, const int* in_sizes, int n_in,
                              void* d_out, int out_size, void* d_ws, size_t ws_size,
                              hipStream_t stream) {
    // setup_inputs() order: output, labels, x_lens, uids, neg_ids
    const float* output  = (const float*)d_in[0];
    const int*   labels  = (const int*)  d_in[1];
    const int*   x_lens  = (const int*)  d_in[2];
    // d_in[3] = uids (unused by the reference math)
    const int*   neg_ids = (const int*)  d_in[4];
    float*       out     = (float*)d_out;

    bpr_loss_kernel<<<1, NTHREADS, 0, stream>>>(output, labels, x_lens, neg_ids, out);
}

// Round 2
// 10.916 us; speedup vs baseline: 1.0337x; 1.0337x over previous
//
#include <hip/hip_runtime.h>
#include <math.h>

// Problem constants from the reference
#define BB 16
#define TT 100
#define VV 50000
#define SS 4
#define NPAIRS (BB * TT)            // 1600
#define NBLK ((NPAIRS + 63) / 64)   // 25 blocks, 1 wave each

// Kernel 1: one (b,t) pair per lane; each block emits one partial sum
// (sum_s log_sigmoid(pos-neg) / x_lens[b], masked by t < x_lens[b]).
__global__ __launch_bounds__(64)
void bpr_partial_kernel(const float* __restrict__ output,
                        const int*   __restrict__ labels,
                        const int*   __restrict__ x_lens,
                        const int*   __restrict__ neg_ids,
                        float*       __restrict__ partials) {
    const int lane = threadIdx.x;
    const int i    = blockIdx.x * 64 + lane;

    float acc = 0.0f;
    if (i < NPAIRS) {
        // Issue all index loads up front (independent, one latency round).
        const int  lab = labels[i];
        const int4 nid = *((const int4*)neg_ids + i);   // SS=4 ints, 16B aligned
        const int  b   = i / TT;
        const int  t   = i - b * TT;
        const int  xl  = x_lens[b];

        if (t < xl) {
            const float* row = output + (size_t)i * VV;  // output[b, t, :]
            // One gather round: pos + 4 negs issue together.
            const float pos = row[lab];
            const float n0  = row[nid.x];
            const float n1  = row[nid.y];
            const float n2  = row[nid.z];
            const float n3  = row[nid.w];

            float s = 0.0f;
            const float xs[4] = {pos - n0, pos - n1, pos - n2, pos - n3};
            #pragma unroll
            for (int s_i = 0; s_i < SS; ++s_i) {
                const float x = xs[s_i];
                // log_sigmoid(x) = min(x,0) - log1p(exp(-|x|))  (stable)
                s += fminf(x, 0.0f) - log1pf(__expf(-fabsf(x)));
            }
            acc = s / (float)xl;
        }
    }

    // Deterministic wave-64 shuffle reduction.
    #pragma unroll
    for (int off = 32; off > 0; off >>= 1)
        acc += __shfl_down(acc, off, 64);

    if (lane == 0)
        partials[blockIdx.x] = acc;
}

// Kernel 2: single wave sums the 25 partials with a fixed tree (deterministic).
__global__ __launch_bounds__(64)
void bpr_final_kernel(const float* __restrict__ partials,
                      float*       __restrict__ out) {
    const int lane = threadIdx.x;
    float v = (lane < NBLK) ? partials[lane] : 0.0f;
    #pragma unroll
    for (int off = 32; off > 0; off >>= 1)
        v += __shfl_down(v, off, 64);
    if (lane == 0)
        out[0] = -v / (float)BB;
}

extern "C" void kernel_launch(void* const* d_in, const int* in_sizes, int n_in,
                              void* d_out, int out_size, void* d_ws, size_t ws_size,
                              hipStream_t stream) {
    // setup_inputs() order: output, labels, x_lens, uids, neg_ids
    const float* output  = (const float*)d_in[0];
    const int*   labels  = (const int*)  d_in[1];
    const int*   x_lens  = (const int*)  d_in[2];
    // d_in[3] = uids (unused by the reference math)
    const int*   neg_ids = (const int*)  d_in[4];
    float*       out     = (float*)d_out;
    float*       partials = (float*)d_ws;   // NBLK floats, overwritten every call

    bpr_partial_kernel<<<NBLK, 64, 0, stream>>>(output, labels, x_lens, neg_ids, partials);
    bpr_final_kernel<<<1, 64, 0, stream>>>(partials, out);
}

// Round 3
// 9.412 us; speedup vs baseline: 1.1989x; 1.1598x over previous
//
#include <hip/hip_runtime.h>
#include <math.h>

// Problem constants from the reference
#define BB 16
#define TT 100
#define VV 50000
#define SS 4
#define NPAIRS (BB * TT)            // 1600
#define NBLK ((NPAIRS + 63) / 64)   // 25 blocks, 1 wave each
#define MAGIC 0x5F3C9A1Bu

// Single fused kernel: 25 blocks gather + wave-reduce their 64 (b,t) pairs,
// publish partials via release-flag; block 0 acquire-spins, does the final
// deterministic fixed-order sum, and writes the scalar result.
__global__ __launch_bounds__(64)
void bpr_fused_kernel(const float* __restrict__ output,
                      const int*   __restrict__ labels,
                      const int*   __restrict__ x_lens,
                      const int*   __restrict__ neg_ids,
                      float*       __restrict__ partials,   // ws
                      unsigned*    __restrict__ flags,      // ws
                      float*       __restrict__ out) {
    const int lane = threadIdx.x;
    const int blk  = blockIdx.x;
    const int i    = blk * 64 + lane;

    float acc = 0.0f;
    if (i < NPAIRS) {
        // Independent index loads issue together (one latency round).
        const int  lab = labels[i];
        const int4 nid = *((const int4*)neg_ids + i);   // SS=4 ints, 16B aligned
        const int  b   = i / TT;
        const int  t   = i - b * TT;
        const int  xl  = x_lens[b];

        if (t < xl) {
            const float* row = output + (size_t)i * VV;  // output[b, t, :]
            // One gather round: pos + 4 negs in flight simultaneously.
            const float pos = row[lab];
            const float n0  = row[nid.x];
            const float n1  = row[nid.y];
            const float n2  = row[nid.z];
            const float n3  = row[nid.w];

            float s = 0.0f;
            const float xs[4] = {pos - n0, pos - n1, pos - n2, pos - n3};
            #pragma unroll
            for (int s_i = 0; s_i < SS; ++s_i) {
                const float x = xs[s_i];
                // log_sigmoid(x) = min(x,0) - log1p(exp(-|x|))  (stable)
                s += fminf(x, 0.0f) - log1pf(__expf(-fabsf(x)));
            }
            acc = s / (float)xl;
        }
    }

    // Deterministic wave-64 shuffle reduction.
    #pragma unroll
    for (int off = 32; off > 0; off >>= 1)
        acc += __shfl_down(acc, off, 64);

    if (lane == 0) {
        __hip_atomic_store(&partials[blk], acc, __ATOMIC_RELAXED, __HIP_MEMORY_SCOPE_AGENT);
        __hip_atomic_store(&flags[blk], MAGIC, __ATOMIC_RELEASE, __HIP_MEMORY_SCOPE_AGENT);
    }

    // Block 0 consumes all partials in fixed order -> bitwise deterministic.
    if (blk == 0) {
        float v = 0.0f;
        if (lane < NBLK) {
            while (__hip_atomic_load(&flags[lane], __ATOMIC_ACQUIRE,
                                     __HIP_MEMORY_SCOPE_AGENT) != MAGIC) {
                __builtin_amdgcn_s_sleep(1);
            }
            v = __hip_atomic_load(&partials[lane], __ATOMIC_RELAXED,
                                  __HIP_MEMORY_SCOPE_AGENT);
        }
        #pragma unroll
        for (int off = 32; off > 0; off >>= 1)
            v += __shfl_down(v, off, 64);
        if (lane == 0)
            out[0] = -v / (float)BB;
    }
}

extern "C" void kernel_launch(void* const* d_in, const int* in_sizes, int n_in,
                              void* d_out, int out_size, void* d_ws, size_t ws_size,
                              hipStream_t stream) {
    // setup_inputs() order: output, labels, x_lens, uids, neg_ids
    const float* output  = (const float*)d_in[0];
    const int*   labels  = (const int*)  d_in[1];
    const int*   x_lens  = (const int*)  d_in[2];
    // d_in[3] = uids (unused by the reference math)
    const int*   neg_ids = (const int*)  d_in[4];
    float*       out     = (float*)d_out;

    float*    partials = (float*)d_ws;                       // 25 floats
    unsigned* flags    = (unsigned*)((char*)d_ws + 128);     // 25 flags, separate line

    bpr_fused_kernel<<<NBLK, 64, 0, stream>>>(output, labels, x_lens, neg_ids,
                                              partials, flags, out);
}